// Round 16
// baseline (355.103 us; speedup 1.0000x reference)
//
#include <hip/hip_runtime.h>
#include <hip/hip_cooperative_groups.h>
#include <math.h>

namespace cg = cooperative_groups;

#define NN 3072
#define FEAT 512
#define HD 64           // 8 heads x 8 dims
#define NE 100000
#define ALPHA 0.2f
#define CAP 96          // max neighbors per row (mean ~7)
#define CAPP 97
#define GRID 1024       // 4 blocks/CU target
#define WHB 768         // coop phase1: blocks 0..767 wh, 768..1023 pre
#define FB_AROWS 8      // fallback attn rows/block
#define FB_WHB 768      // fallback fused stage1 wh blocks
#define K5_BLOCKS 2048  // fallback cls grid

// ================= cooperative mega-kernel (union LDS = 14.6 KB) =================
__global__ __launch_bounds__(256, 4) void k_all(
    const float* __restrict__ adj, const float* __restrict__ x, const float* __restrict__ W,
    const float* __restrict__ a1, const float* __restrict__ a2, const float* __restrict__ W1,
    const float* __restrict__ b1, const float* __restrict__ W2, const float* __restrict__ b2,
    const int* __restrict__ L, const int* __restrict__ R, const int* __restrict__ label,
    float* __restrict__ Wh, float* __restrict__ s1t, float* __restrict__ s2t,
    int* __restrict__ cnt, int* __restrict__ nbr, float* __restrict__ P, float* __restrict__ Q,
    float* __restrict__ partials, float* __restrict__ out)
{
    cg::grid_group grid = cg::this_grid();
    __shared__ union {
        struct { float xs[4][FEAT]; float part[4][4][HD]; } wh;                  // 12288 B
        struct { int wcnt[4]; } pre;
        struct { int jbuf[4][CAP]; float ebuf[4][8][CAPP]; float es[4][HD]; } at; // 14976 B
        struct { float wsum[4]; } cls;
        struct { float red[256]; } rd;
    } u;
    int b = blockIdx.x, tid = threadIdx.x;
    int wid = tid >> 6, lane = tid & 63;

    // ---- phase 1: wh (b<768) || pre (b>=768) ----
    if (b < WHB) {
        int n0 = b * 4;
        for (int idx = tid; idx < 512; idx += 256) {
            int r = idx >> 7, fq = idx & 127;
            *(float4*)&u.wh.xs[r][fq * 4] = ((const float4*)x)[(size_t)(n0 + r) * (FEAT / 4) + fq];
        }
        __syncthreads();
        int fsub = lane >> 4, h = (lane >> 1) & 7, dq = lane & 1;
        const float4* W4 = (const float4*)W;
        int base4 = h * 1024 + dq;
        int f0 = wid * (FEAT / 4);
        float4 acc0 = {0.f,0.f,0.f,0.f}, acc1 = acc0, acc2 = acc0, acc3 = acc0;
        #pragma unroll 4
        for (int f4 = 0; f4 < 32; ++f4) {
            int f = f0 + f4 * 4 + fsub;
            float4 w4 = W4[base4 + f * 2];
            float x0 = u.wh.xs[0][f], x1 = u.wh.xs[1][f], x2 = u.wh.xs[2][f], x3 = u.wh.xs[3][f];
            acc0.x = fmaf(x0, w4.x, acc0.x); acc0.y = fmaf(x0, w4.y, acc0.y);
            acc0.z = fmaf(x0, w4.z, acc0.z); acc0.w = fmaf(x0, w4.w, acc0.w);
            acc1.x = fmaf(x1, w4.x, acc1.x); acc1.y = fmaf(x1, w4.y, acc1.y);
            acc1.z = fmaf(x1, w4.z, acc1.z); acc1.w = fmaf(x1, w4.w, acc1.w);
            acc2.x = fmaf(x2, w4.x, acc2.x); acc2.y = fmaf(x2, w4.y, acc2.y);
            acc2.z = fmaf(x2, w4.z, acc2.z); acc2.w = fmaf(x2, w4.w, acc2.w);
            acc3.x = fmaf(x3, w4.x, acc3.x); acc3.y = fmaf(x3, w4.y, acc3.y);
            acc3.z = fmaf(x3, w4.z, acc3.z); acc3.w = fmaf(x3, w4.w, acc3.w);
        }
        #define RED4(A) \
            A.x += __shfl_xor(A.x, 16, 64); A.x += __shfl_xor(A.x, 32, 64); \
            A.y += __shfl_xor(A.y, 16, 64); A.y += __shfl_xor(A.y, 32, 64); \
            A.z += __shfl_xor(A.z, 16, 64); A.z += __shfl_xor(A.z, 32, 64); \
            A.w += __shfl_xor(A.w, 16, 64); A.w += __shfl_xor(A.w, 32, 64);
        RED4(acc0) RED4(acc1) RED4(acc2) RED4(acc3)
        #undef RED4
        if (fsub == 0) {
            int o = h * 8 + dq * 4;
            *(float4*)&u.wh.part[wid][0][o] = acc0;
            *(float4*)&u.wh.part[wid][1][o] = acc1;
            *(float4*)&u.wh.part[wid][2][o] = acc2;
            *(float4*)&u.wh.part[wid][3][o] = acc3;
        }
        __syncthreads();
        int n = n0 + wid;
        float v = u.wh.part[0][wid][lane] + u.wh.part[1][wid][lane]
                + u.wh.part[2][wid][lane] + u.wh.part[3][wid][lane];
        Wh[n * HD + lane] = v;
        float t1 = v * a1[lane];
        float t2 = v * a2[lane];
        for (int m = 1; m < 8; m <<= 1) {
            t1 += __shfl_xor(t1, m, 64);
            t2 += __shfl_xor(t2, m, 64);
        }
        if ((lane & 7) == 0) {
            int h2 = lane >> 3;
            s1t[n * 8 + h2] = t1;
            s2t[n * 8 + h2] = t2;
        }
    } else {
        unsigned long long lmask = (1ull << lane) - 1ull;
        int i = b - WHB;                      // 12 rows per block, stride 256, 2-deep prefetch
        float4 v[3], nx[3];
        {
            const float4* r0 = (const float4*)&adj[(size_t)i * NN];
            #pragma unroll
            for (int c = 0; c < 3; ++c) v[c] = r0[wid * 192 + c * 64 + lane];
        }
        for (; i < NN; i += 256) {
            int inext = i + 256;
            if (inext < NN) {
                const float4* rn = (const float4*)&adj[(size_t)inext * NN];
                #pragma unroll
                for (int c = 0; c < 3; ++c) nx[c] = rn[wid * 192 + c * 64 + lane];
            }
            int wc = 0;
            unsigned long long masks[12];
            #pragma unroll
            for (int c = 0; c < 3; ++c) {
                #pragma unroll
                for (int k = 0; k < 4; ++k) {
                    float vk = k == 0 ? v[c].x : k == 1 ? v[c].y : k == 2 ? v[c].z : v[c].w;
                    unsigned long long m = __ballot(vk > 0.f);
                    masks[c * 4 + k] = m;
                    wc += __popcll(m);
                }
            }
            if (lane == 0) u.pre.wcnt[wid] = wc;
            __syncthreads();
            int base = 0;
            #pragma unroll
            for (int w2 = 0; w2 < 4; ++w2) if (w2 < wid) base += u.pre.wcnt[w2];
            #pragma unroll
            for (int c = 0; c < 3; ++c) {
                #pragma unroll
                for (int k = 0; k < 4; ++k) {
                    unsigned long long m = masks[c * 4 + k];
                    if ((m >> lane) & 1ull) {
                        int pos = base + __popcll(m & lmask);
                        if (pos < CAP) nbr[i * CAP + pos] = wid * 768 + c * 256 + lane * 4 + k;
                    }
                    base += __popcll(m);
                }
            }
            if (tid == 0) {
                int tot = u.pre.wcnt[0] + u.pre.wcnt[1] + u.pre.wcnt[2] + u.pre.wcnt[3];
                cnt[i] = tot < CAP ? tot : CAP;
            }
            __syncthreads();
            #pragma unroll
            for (int c = 0; c < 3; ++c) v[c] = nx[c];
        }
    }
    grid.sync();

    // ---- phase 2: attn + ELU + P/Q (blocks < 768; 4 rows each; W1 from L2) ----
    if (b < WHB) {
        int i = b * 4 + wid;
        int h = lane >> 3, d = lane & 7;
        int ni = cnt[i];
        float s1i = s1t[i * 8 + h];
        for (int k = lane; k < CAP; k += 64)
            if (k < ni) u.at.jbuf[wid][k] = nbr[i * CAP + k];
        float mloc = -INFINITY;
        for (int k = d; k < ni; k += 8) {
            int j = u.at.jbuf[wid][k];
            float ev = s1i + s2t[j * 8 + h];
            ev = ev > 0.f ? ev : ALPHA * ev;
            u.at.ebuf[wid][h][k] = ev;
            mloc = fmaxf(mloc, ev);
        }
        mloc = fmaxf(mloc, __shfl_xor(mloc, 1, 8));
        mloc = fmaxf(mloc, __shfl_xor(mloc, 2, 8));
        mloc = fmaxf(mloc, __shfl_xor(mloc, 4, 8));
        float den0 = 0.f, den1 = 0.f, ac0 = 0.f, ac1 = 0.f;
        int k = 0;
        for (; k + 1 < ni; k += 2) {
            int j0 = u.at.jbuf[wid][k], j1 = u.at.jbuf[wid][k + 1];
            float p0 = __expf(u.at.ebuf[wid][h][k] - mloc);
            float p1 = __expf(u.at.ebuf[wid][h][k + 1] - mloc);
            float w0 = Wh[j0 * HD + lane], w1 = Wh[j1 * HD + lane];
            den0 += p0; den1 += p1;
            ac0 = fmaf(p0, w0, ac0);
            ac1 = fmaf(p1, w1, ac1);
        }
        if (k < ni) {
            float p0 = __expf(u.at.ebuf[wid][h][k] - mloc);
            den0 += p0;
            ac0 = fmaf(p0, Wh[u.at.jbuf[wid][k] * HD + lane], ac0);
        }
        float o = (ac0 + ac1) / (den0 + den1);
        o = o > 0.f ? o : expm1f(o);
        u.at.es[wid][lane] = o;                 // wave-private slice: no block sync needed
        float p = b1[lane], q = 0.f;
        #pragma unroll 8
        for (int kk = 0; kk < HD; ++kk) {
            float e = u.at.es[wid][kk];
            p = fmaf(e, W1[kk * HD + lane], p);          // coalesced 256B, L2-resident
            q = fmaf(e, W1[(HD + kk) * HD + lane], q);
        }
        P[i * HD + lane] = p;
        Q[i * HD + lane] = q;
    }
    grid.sync();

    // ---- phase 3: edge classifier (all 1024 blocks) ----
    {
        int sl = tid & 15;
        int g = (b * 256 + tid) >> 4;                    // 0..16383
        float2 wa = *(const float2*)&W2[(sl * 4 + 0) * 2];
        float2 wb = *(const float2*)&W2[(sl * 4 + 1) * 2];
        float2 wc = *(const float2*)&W2[(sl * 4 + 2) * 2];
        float2 wd = *(const float2*)&W2[(sl * 4 + 3) * 2];
        float b20 = b2[0], b21 = b2[1];
        float sum = 0.f;
        #pragma unroll
        for (int bb = 0; bb < 2; ++bb) {
            int e0 = g + bb * 49152, e1 = e0 + 16384, e2 = e0 + 32768;
            int ln0 = L[e0], rn0 = R[e0], lb0 = label[e0];
            int ln1 = L[e1], rn1 = R[e1], lb1 = label[e1];
            int ln2 = L[e2], rn2 = R[e2], lb2 = label[e2];
            float4 p0 = *(const float4*)&P[ln0 * HD + sl * 4];
            float4 q0 = *(const float4*)&Q[rn0 * HD + sl * 4];
            float4 p1 = *(const float4*)&P[ln1 * HD + sl * 4];
            float4 q1 = *(const float4*)&Q[rn1 * HD + sl * 4];
            float4 p2 = *(const float4*)&P[ln2 * HD + sl * 4];
            float4 q2 = *(const float4*)&Q[rn2 * HD + sl * 4];
            float v00 = fmaxf(p0.x + q0.x, 0.f), v01 = fmaxf(p0.y + q0.y, 0.f);
            float v02 = fmaxf(p0.z + q0.z, 0.f), v03 = fmaxf(p0.w + q0.w, 0.f);
            float v10 = fmaxf(p1.x + q1.x, 0.f), v11 = fmaxf(p1.y + q1.y, 0.f);
            float v12 = fmaxf(p1.z + q1.z, 0.f), v13 = fmaxf(p1.w + q1.w, 0.f);
            float v20 = fmaxf(p2.x + q2.x, 0.f), v21 = fmaxf(p2.y + q2.y, 0.f);
            float v22 = fmaxf(p2.z + q2.z, 0.f), v23 = fmaxf(p2.w + q2.w, 0.f);
            float t00 = v00 * wa.x + v01 * wb.x + v02 * wc.x + v03 * wd.x;
            float t01 = v00 * wa.y + v01 * wb.y + v02 * wc.y + v03 * wd.y;
            float t10 = v10 * wa.x + v11 * wb.x + v12 * wc.x + v13 * wd.x;
            float t11 = v10 * wa.y + v11 * wb.y + v12 * wc.y + v13 * wd.y;
            float t20 = v20 * wa.x + v21 * wb.x + v22 * wc.x + v23 * wd.x;
            float t21 = v20 * wa.y + v21 * wb.y + v22 * wc.y + v23 * wd.y;
            #pragma unroll
            for (int m = 1; m < 16; m <<= 1) {
                t00 += __shfl_xor(t00, m, 64);  t01 += __shfl_xor(t01, m, 64);
                t10 += __shfl_xor(t10, m, 64);  t11 += __shfl_xor(t11, m, 64);
                t20 += __shfl_xor(t20, m, 64);  t21 += __shfl_xor(t21, m, 64);
            }
            float l0 = t00 + b20, l1 = t01 + b21;
            float mx = fmaxf(l0, l1);
            sum += mx + __logf(__expf(l0 - mx) + __expf(l1 - mx)) - (lb0 ? l1 : l0);
            l0 = t10 + b20; l1 = t11 + b21; mx = fmaxf(l0, l1);
            sum += mx + __logf(__expf(l0 - mx) + __expf(l1 - mx)) - (lb1 ? l1 : l0);
            l0 = t20 + b20; l1 = t21 + b21; mx = fmaxf(l0, l1);
            sum += mx + __logf(__expf(l0 - mx) + __expf(l1 - mx)) - (lb2 ? l1 : l0);
        }
        if (g + 98304 < NE) {                            // tail; wave-uniform
            int e3 = g + 98304;
            int ln3 = L[e3], rn3 = R[e3], lb3 = label[e3];
            float4 p3 = *(const float4*)&P[ln3 * HD + sl * 4];
            float4 q3 = *(const float4*)&Q[rn3 * HD + sl * 4];
            float w0 = fmaxf(p3.x + q3.x, 0.f), w1 = fmaxf(p3.y + q3.y, 0.f);
            float w2 = fmaxf(p3.z + q3.z, 0.f), w3 = fmaxf(p3.w + q3.w, 0.f);
            float t30 = w0 * wa.x + w1 * wb.x + w2 * wc.x + w3 * wd.x;
            float t31 = w0 * wa.y + w1 * wb.y + w2 * wc.y + w3 * wd.y;
            #pragma unroll
            for (int m = 1; m < 16; m <<= 1) {
                t30 += __shfl_xor(t30, m, 64);  t31 += __shfl_xor(t31, m, 64);
            }
            float l0 = t30 + b20, l1 = t31 + b21;
            float mx = fmaxf(l0, l1);
            sum += mx + __logf(__expf(l0 - mx) + __expf(l1 - mx)) - (lb3 ? l1 : l0);
        }
        sum = (sl == 0) ? sum : 0.f;
        #pragma unroll
        for (int m = 1; m < 64; m <<= 1) sum += __shfl_xor(sum, m, 64);
        if ((tid & 63) == 0) u.cls.wsum[tid >> 6] = sum;
        __syncthreads();
        if (tid == 0) partials[b] = u.cls.wsum[0] + u.cls.wsum[1] + u.cls.wsum[2] + u.cls.wsum[3];
    }
    grid.sync();

    // ---- phase 4: final reduce (block 0) ----
    if (b == 0) {
        float s = partials[tid] + partials[tid + 256] + partials[tid + 512] + partials[tid + 768];
        u.rd.red[tid] = s;
        __syncthreads();
        for (int st = 128; st > 0; st >>= 1) {
            if (tid < st) u.rd.red[tid] += u.rd.red[tid + st];
            __syncthreads();
        }
        if (tid == 0) out[0] = u.rd.red[0] / (float)NE;
    }
}

// ================= fallback: proven R10 pipeline (34.7 us) =================
__global__ __launch_bounds__(256) void k_stage1(const float* __restrict__ adj, const float* __restrict__ x,
                                                const float* __restrict__ W, const float* __restrict__ a1,
                                                const float* __restrict__ a2, int* __restrict__ nbr,
                                                int* __restrict__ cnt, float* __restrict__ Wh,
                                                float* __restrict__ s1t, float* __restrict__ s2t) {
    __shared__ float xs[4][FEAT];
    __shared__ float part[4][4][HD];
    __shared__ int   wcnt[4];
    int b = blockIdx.x;
    int tid = threadIdx.x;
    int wid = tid >> 6, lane = tid & 63;
    if (b >= FB_WHB) {
        int i = b - FB_WHB;
        const float4* row4 = (const float4*)&adj[(size_t)i * NN];
        float4 v[3];
        #pragma unroll
        for (int c = 0; c < 3; ++c) v[c] = row4[wid * 192 + c * 64 + lane];
        unsigned long long lmask = (1ull << lane) - 1ull;
        int wc = 0;
        unsigned long long masks[12];
        #pragma unroll
        for (int c = 0; c < 3; ++c) {
            #pragma unroll
            for (int k = 0; k < 4; ++k) {
                float vk = k == 0 ? v[c].x : k == 1 ? v[c].y : k == 2 ? v[c].z : v[c].w;
                unsigned long long m = __ballot(vk > 0.f);
                masks[c * 4 + k] = m;
                wc += __popcll(m);
            }
        }
        if (lane == 0) wcnt[wid] = wc;
        __syncthreads();
        int base = 0;
        #pragma unroll
        for (int w2 = 0; w2 < 4; ++w2) if (w2 < wid) base += wcnt[w2];
        #pragma unroll
        for (int c = 0; c < 3; ++c) {
            #pragma unroll
            for (int k = 0; k < 4; ++k) {
                unsigned long long m = masks[c * 4 + k];
                if ((m >> lane) & 1ull) {
                    int pos = base + __popcll(m & lmask);
                    if (pos < CAP) nbr[i * CAP + pos] = wid * 768 + c * 256 + lane * 4 + k;
                }
                base += __popcll(m);
            }
        }
        if (tid == 0) {
            int tot = wcnt[0] + wcnt[1] + wcnt[2] + wcnt[3];
            cnt[i] = tot < CAP ? tot : CAP;
        }
    } else {
        int n0 = b * 4;
        for (int idx = tid; idx < 512; idx += 256) {
            int r = idx >> 7, fq = idx & 127;
            *(float4*)&xs[r][fq * 4] = ((const float4*)x)[(size_t)(n0 + r) * (FEAT / 4) + fq];
        }
        __syncthreads();
        int fsub = lane >> 4, h = (lane >> 1) & 7, dq = lane & 1;
        const float4* W4 = (const float4*)W;
        int base4 = h * 1024 + dq;
        int f0 = wid * (FEAT / 4);
        float4 acc0 = {0.f,0.f,0.f,0.f}, acc1 = acc0, acc2 = acc0, acc3 = acc0;
        #pragma unroll 4
        for (int f4 = 0; f4 < 32; ++f4) {
            int f = f0 + f4 * 4 + fsub;
            float4 w4 = W4[base4 + f * 2];
            float x0 = xs[0][f], x1 = xs[1][f], x2 = xs[2][f], x3 = xs[3][f];
            acc0.x = fmaf(x0, w4.x, acc0.x); acc0.y = fmaf(x0, w4.y, acc0.y);
            acc0.z = fmaf(x0, w4.z, acc0.z); acc0.w = fmaf(x0, w4.w, acc0.w);
            acc1.x = fmaf(x1, w4.x, acc1.x); acc1.y = fmaf(x1, w4.y, acc1.y);
            acc1.z = fmaf(x1, w4.z, acc1.z); acc1.w = fmaf(x1, w4.w, acc1.w);
            acc2.x = fmaf(x2, w4.x, acc2.x); acc2.y = fmaf(x2, w4.y, acc2.y);
            acc2.z = fmaf(x2, w4.z, acc2.z); acc2.w = fmaf(x2, w4.w, acc2.w);
            acc3.x = fmaf(x3, w4.x, acc3.x); acc3.y = fmaf(x3, w4.y, acc3.y);
            acc3.z = fmaf(x3, w4.z, acc3.z); acc3.w = fmaf(x3, w4.w, acc3.w);
        }
        #define RED4(A) \
            A.x += __shfl_xor(A.x, 16, 64); A.x += __shfl_xor(A.x, 32, 64); \
            A.y += __shfl_xor(A.y, 16, 64); A.y += __shfl_xor(A.y, 32, 64); \
            A.z += __shfl_xor(A.z, 16, 64); A.z += __shfl_xor(A.z, 32, 64); \
            A.w += __shfl_xor(A.w, 16, 64); A.w += __shfl_xor(A.w, 32, 64);
        RED4(acc0) RED4(acc1) RED4(acc2) RED4(acc3)
        #undef RED4
        if (fsub == 0) {
            int o = h * 8 + dq * 4;
            *(float4*)&part[wid][0][o] = acc0;
            *(float4*)&part[wid][1][o] = acc1;
            *(float4*)&part[wid][2][o] = acc2;
            *(float4*)&part[wid][3][o] = acc3;
        }
        __syncthreads();
        int n = n0 + wid;
        float v = part[0][wid][lane] + part[1][wid][lane] + part[2][wid][lane] + part[3][wid][lane];
        Wh[n * HD + lane] = v;
        float t1 = v * a1[lane];
        float t2 = v * a2[lane];
        for (int m = 1; m < 8; m <<= 1) {
            t1 += __shfl_xor(t1, m, 64);
            t2 += __shfl_xor(t2, m, 64);
        }
        if ((lane & 7) == 0) {
            int h2 = lane >> 3;
            s1t[n * 8 + h2] = t1;
            s2t[n * 8 + h2] = t2;
        }
    }
}

__global__ __launch_bounds__(512) void k_attn_pq(const float* __restrict__ Wh, const float* __restrict__ s1t,
                                                 const float* __restrict__ s2t, const int* __restrict__ nbr,
                                                 const int* __restrict__ cnt, const float* __restrict__ W1,
                                                 const float* __restrict__ b1, float* __restrict__ P,
                                                 float* __restrict__ Q) {
    __shared__ float W1s[2 * HD][HD];
    __shared__ int   jbuf[FB_AROWS][CAP];
    __shared__ float ebuf[FB_AROWS][8][CAPP];
    __shared__ float es[FB_AROWS][HD];
    int tid = threadIdx.x;
    int wid = tid >> 6;
    int lane = tid & 63;
    int i = blockIdx.x * FB_AROWS + wid;
    int h = lane >> 3, d = lane & 7;
    int ni = cnt[i];
    float s1i = s1t[i * 8 + h];
    for (int k = lane; k < CAP; k += 64)
        if (k < ni) jbuf[wid][k] = nbr[i * CAP + k];
    for (int idx = tid; idx < 2048; idx += 512)
        ((float4*)W1s)[idx] = ((const float4*)W1)[idx];
    __syncthreads();
    float mloc = -INFINITY;
    for (int k = d; k < ni; k += 8) {
        int j = jbuf[wid][k];
        float ev = s1i + s2t[j * 8 + h];
        ev = ev > 0.f ? ev : ALPHA * ev;
        ebuf[wid][h][k] = ev;
        mloc = fmaxf(mloc, ev);
    }
    mloc = fmaxf(mloc, __shfl_xor(mloc, 1, 8));
    mloc = fmaxf(mloc, __shfl_xor(mloc, 2, 8));
    mloc = fmaxf(mloc, __shfl_xor(mloc, 4, 8));
    __syncthreads();
    float denom = 0.f, acc = 0.f;
    for (int k = 0; k < ni; ++k) {
        float p = __expf(ebuf[wid][h][k] - mloc);
        denom += p;
        acc = fmaf(p, Wh[jbuf[wid][k] * HD + lane], acc);
    }
    float o = acc / denom;
    o = o > 0.f ? o : expm1f(o);
    es[wid][lane] = o;
    __syncthreads();
    float p = b1[lane], q = 0.f;
    #pragma unroll 8
    for (int k = 0; k < HD; ++k) {
        float e = es[wid][k];
        p = fmaf(e, W1s[k][lane], p);
        q = fmaf(e, W1s[HD + k][lane], q);
    }
    P[i * HD + lane] = p;
    Q[i * HD + lane] = q;
}

__global__ __launch_bounds__(256) void k_cls(const float* __restrict__ P, const float* __restrict__ Q,
                                             const int* __restrict__ L, const int* __restrict__ R,
                                             const int* __restrict__ label, const float* __restrict__ W2,
                                             const float* __restrict__ b2, float* __restrict__ partials) {
    int tid = threadIdx.x;
    int sl = tid & 15;
    int g = (blockIdx.x * 256 + tid) >> 4;
    float2 wa = *(const float2*)&W2[(sl * 4 + 0) * 2];
    float2 wb = *(const float2*)&W2[(sl * 4 + 1) * 2];
    float2 wc = *(const float2*)&W2[(sl * 4 + 2) * 2];
    float2 wd = *(const float2*)&W2[(sl * 4 + 3) * 2];
    float b20 = b2[0], b21 = b2[1];
    int e0 = g, e1 = g + 32768, e2 = g + 65536;
    int ln0 = L[e0], rn0 = R[e0], lb0 = label[e0];
    int ln1 = L[e1], rn1 = R[e1], lb1 = label[e1];
    int ln2 = L[e2], rn2 = R[e2], lb2 = label[e2];
    float4 p0 = *(const float4*)&P[ln0 * HD + sl * 4];
    float4 q0 = *(const float4*)&Q[rn0 * HD + sl * 4];
    float4 p1 = *(const float4*)&P[ln1 * HD + sl * 4];
    float4 q1 = *(const float4*)&Q[rn1 * HD + sl * 4];
    float4 p2 = *(const float4*)&P[ln2 * HD + sl * 4];
    float4 q2 = *(const float4*)&Q[rn2 * HD + sl * 4];
    float v00 = fmaxf(p0.x + q0.x, 0.f), v01 = fmaxf(p0.y + q0.y, 0.f);
    float v02 = fmaxf(p0.z + q0.z, 0.f), v03 = fmaxf(p0.w + q0.w, 0.f);
    float v10 = fmaxf(p1.x + q1.x, 0.f), v11 = fmaxf(p1.y + q1.y, 0.f);
    float v12 = fmaxf(p1.z + q1.z, 0.f), v13 = fmaxf(p1.w + q1.w, 0.f);
    float v20 = fmaxf(p2.x + q2.x, 0.f), v21 = fmaxf(p2.y + q2.y, 0.f);
    float v22 = fmaxf(p2.z + q2.z, 0.f), v23 = fmaxf(p2.w + q2.w, 0.f);
    float t00 = v00 * wa.x + v01 * wb.x + v02 * wc.x + v03 * wd.x;
    float t01 = v00 * wa.y + v01 * wb.y + v02 * wc.y + v03 * wd.y;
    float t10 = v10 * wa.x + v11 * wb.x + v12 * wc.x + v13 * wd.x;
    float t11 = v10 * wa.y + v11 * wb.y + v12 * wc.y + v13 * wd.y;
    float t20 = v20 * wa.x + v21 * wb.x + v22 * wc.x + v23 * wd.x;
    float t21 = v20 * wa.y + v21 * wb.y + v22 * wc.y + v23 * wd.y;
    #pragma unroll
    for (int m = 1; m < 16; m <<= 1) {
        t00 += __shfl_xor(t00, m, 64);  t01 += __shfl_xor(t01, m, 64);
        t10 += __shfl_xor(t10, m, 64);  t11 += __shfl_xor(t11, m, 64);
        t20 += __shfl_xor(t20, m, 64);  t21 += __shfl_xor(t21, m, 64);
    }
    float sum;
    {
        float l0 = t00 + b20, l1 = t01 + b21;
        float mx = fmaxf(l0, l1);
        sum = mx + __logf(__expf(l0 - mx) + __expf(l1 - mx)) - (lb0 ? l1 : l0);
        l0 = t10 + b20; l1 = t11 + b21; mx = fmaxf(l0, l1);
        sum += mx + __logf(__expf(l0 - mx) + __expf(l1 - mx)) - (lb1 ? l1 : l0);
        l0 = t20 + b20; l1 = t21 + b21; mx = fmaxf(l0, l1);
        sum += mx + __logf(__expf(l0 - mx) + __expf(l1 - mx)) - (lb2 ? l1 : l0);
    }
    if (g + 98304 < NE) {
        int e3 = g + 98304;
        int ln3 = L[e3], rn3 = R[e3], lb3 = label[e3];
        float4 p3 = *(const float4*)&P[ln3 * HD + sl * 4];
        float4 q3 = *(const float4*)&Q[rn3 * HD + sl * 4];
        float w0 = fmaxf(p3.x + q3.x, 0.f), w1 = fmaxf(p3.y + q3.y, 0.f);
        float w2 = fmaxf(p3.z + q3.z, 0.f), w3 = fmaxf(p3.w + q3.w, 0.f);
        float t30 = w0 * wa.x + w1 * wb.x + w2 * wc.x + w3 * wd.x;
        float t31 = w0 * wa.y + w1 * wb.y + w2 * wc.y + w3 * wd.y;
        #pragma unroll
        for (int m = 1; m < 16; m <<= 1) {
            t30 += __shfl_xor(t30, m, 64);  t31 += __shfl_xor(t31, m, 64);
        }
        float l0 = t30 + b20, l1 = t31 + b21;
        float mx = fmaxf(l0, l1);
        sum += mx + __logf(__expf(l0 - mx) + __expf(l1 - mx)) - (lb3 ? l1 : l0);
    }
    sum = (sl == 0) ? sum : 0.f;
    #pragma unroll
    for (int m = 1; m < 64; m <<= 1) sum += __shfl_xor(sum, m, 64);
    __shared__ float wsum[4];
    if ((tid & 63) == 0) wsum[tid >> 6] = sum;
    __syncthreads();
    if (tid == 0) partials[blockIdx.x] = wsum[0] + wsum[1] + wsum[2] + wsum[3];
}

__global__ __launch_bounds__(1024) void k_reduce(const float* __restrict__ partials, float* __restrict__ out) {
    __shared__ float sh[1024];
    int t = threadIdx.x;
    sh[t] = partials[t] + partials[t + 1024];
    __syncthreads();
    for (int s = 512; s > 0; s >>= 1) {
        if (t < s) sh[t] += sh[t + s];
        __syncthreads();
    }
    if (t == 0) out[0] = sh[0] / (float)NE;
}

extern "C" void kernel_launch(void* const* d_in, const int* in_sizes, int n_in,
                              void* d_out, int out_size, void* d_ws, size_t ws_size,
                              hipStream_t stream) {
    const float* x     = (const float*)d_in[0];
    const float* adj   = (const float*)d_in[1];
    const int*   L     = (const int*)d_in[2];
    const int*   R     = (const int*)d_in[3];
    const int*   label = (const int*)d_in[4];
    const float* W     = (const float*)d_in[5];
    const float* a1    = (const float*)d_in[6];
    const float* a2    = (const float*)d_in[7];
    const float* W1    = (const float*)d_in[8];
    const float* b1    = (const float*)d_in[9];
    const float* W2    = (const float*)d_in[10];
    const float* b2    = (const float*)d_in[11];

    char* ws = (char*)d_ws;
    float* Wh       = (float*)(ws + 0);         //  786432 B
    float* s1t      = (float*)(ws + 786432);    //   98304 B
    float* s2t      = (float*)(ws + 884736);    //   98304 B
    int*   cnt      = (int*)  (ws + 983040);    //   12288 B
    int*   nbr      = (int*)  (ws + 995328);    // 1179648 B
    float* P        = (float*)(ws + 2174976);   //  786432 B
    float* Q        = (float*)(ws + 2961408);   //  786432 B
    float* partials = (float*)(ws + 3747840);   //    8192 B
    float* outp     = (float*)d_out;

    // Gate the cooperative path on capability + occupancy (pure host queries,
    // deterministic, graph-capture-safe). Fall back to the proven 4-kernel
    // pipeline otherwise — identical math, different summation grouping.
    int dev = 0;
    hipGetDevice(&dev);
    int coop = 0;
    hipDeviceGetAttribute(&coop, hipDeviceAttributeCooperativeLaunch, dev);
    int nb = 0;
    if (coop) hipOccupancyMaxActiveBlocksPerMultiprocessor(&nb, k_all, 256, 0);
    if (coop && nb >= 4) {
        void* args[] = {(void*)&adj, (void*)&x, (void*)&W, (void*)&a1, (void*)&a2, (void*)&W1,
                        (void*)&b1, (void*)&W2, (void*)&b2, (void*)&L, (void*)&R, (void*)&label,
                        (void*)&Wh, (void*)&s1t, (void*)&s2t, (void*)&cnt, (void*)&nbr,
                        (void*)&P, (void*)&Q, (void*)&partials, (void*)&outp};
        hipError_t e = hipLaunchCooperativeKernel((const void*)k_all, dim3(GRID), dim3(256),
                                                  args, 0, stream);
        if (e == hipSuccess) return;
    }
    k_stage1<<<FB_WHB + NN, 256, 0, stream>>>(adj, x, W, a1, a2, nbr, cnt, Wh, s1t, s2t);
    k_attn_pq<<<NN / FB_AROWS, 512, 0, stream>>>(Wh, s1t, s2t, nbr, cnt, W1, b1, P, Q);
    k_cls<<<K5_BLOCKS, 256, 0, stream>>>(P, Q, L, R, label, W2, b2, partials);
    k_reduce<<<1, 1024, 0, stream>>>(partials, outp);
}

// Round 17
// 60.497 us; speedup vs baseline: 5.8697x; 5.8697x over previous
//
#include <hip/hip_runtime.h>
#include <math.h>

#define NN 3072
#define FEAT 512
#define HD 64           // 8 heads x 8 dims
#define NE 100000
#define ALPHA 0.2f
#define CAP 96          // max neighbors per row (mean ~7)
#define CAPP 97
#define AROWS 8         // attn rows per block (8 waves)
#define WHB2 1536       // wh role: 2 rows per block -> 6144 waves (2x R10)
#define K5_BLOCKS 2048

// K1 (fused): b < 1536: wh role (2 rows, K split over 4 waves, float4-over-d W loads);
//             b >= 1536: pre role (1 adj row, 4 waves x 768 cols) — R10 verbatim.
//             Block 0 also zeroes out[0] for K3's atomic accumulation.
__global__ __launch_bounds__(256) void k_stage1(const float* __restrict__ adj, const float* __restrict__ x,
                                                const float* __restrict__ W, const float* __restrict__ a1,
                                                const float* __restrict__ a2, int* __restrict__ nbr,
                                                int* __restrict__ cnt, float* __restrict__ Wh,
                                                float* __restrict__ s1t, float* __restrict__ s2t,
                                                float* __restrict__ out) {
    __shared__ float xs[2][FEAT];       // 4 KB (wh)
    __shared__ float part[4][2][HD];    // 2 KB (wh)
    __shared__ int   wcnt[4];           // (pre)
    int b = blockIdx.x;
    int tid = threadIdx.x;
    int wid = tid >> 6, lane = tid & 63;
    if (b == 0 && tid == 0) out[0] = 0.f;    // reset atomic accumulator every call

    if (b >= WHB2) {
        // ---- pre role: row i, wave wid scans cols [wid*768, wid*768+768) ----
        int i = b - WHB2;
        const float4* row4 = (const float4*)&adj[(size_t)i * NN];
        float4 v[3];
        #pragma unroll
        for (int c = 0; c < 3; ++c) v[c] = row4[wid * 192 + c * 64 + lane];
        unsigned long long lmask = (1ull << lane) - 1ull;
        int wc = 0;
        unsigned long long masks[12];
        #pragma unroll
        for (int c = 0; c < 3; ++c) {
            #pragma unroll
            for (int k = 0; k < 4; ++k) {
                float vk = k == 0 ? v[c].x : k == 1 ? v[c].y : k == 2 ? v[c].z : v[c].w;
                unsigned long long m = __ballot(vk > 0.f);
                masks[c * 4 + k] = m;
                wc += __popcll(m);
            }
        }
        if (lane == 0) wcnt[wid] = wc;
        __syncthreads();
        int base = 0;
        #pragma unroll
        for (int w2 = 0; w2 < 4; ++w2) if (w2 < wid) base += wcnt[w2];
        #pragma unroll
        for (int c = 0; c < 3; ++c) {
            #pragma unroll
            for (int k = 0; k < 4; ++k) {
                unsigned long long m = masks[c * 4 + k];
                if ((m >> lane) & 1ull) {
                    int pos = base + __popcll(m & lmask);
                    if (pos < CAP) nbr[i * CAP + pos] = wid * 768 + c * 256 + lane * 4 + k;
                }
                base += __popcll(m);
            }
        }
        if (tid == 0) {
            int tot = wcnt[0] + wcnt[1] + wcnt[2] + wcnt[3];
            cnt[i] = tot < CAP ? tot : CAP;
        }
    } else {
        // ---- wh role: rows n0, n0+1; K split over 4 waves (6144 waves total) ----
        int n0 = b * 2;
        for (int idx = tid; idx < 256; idx += 256) {}        // (no-op placeholder removed below)
        {
            int idx = tid;                                   // 256 float4 = 2 rows of x
            int r = idx >> 7, fq = idx & 127;
            *(float4*)&xs[r][fq * 4] = ((const float4*)x)[(size_t)(n0 + r) * (FEAT / 4) + fq];
        }
        __syncthreads();
        int fsub = lane >> 4, h = (lane >> 1) & 7, dq = lane & 1;
        const float4* W4 = (const float4*)W;
        int base4 = h * 1024 + dq;                           // + f*2 -> W[h][f][dq*4..+3]
        int f0 = wid * (FEAT / 4);
        float4 acc0 = {0.f,0.f,0.f,0.f}, acc1 = acc0;
        #pragma unroll 4
        for (int f4 = 0; f4 < 32; ++f4) {
            int f = f0 + f4 * 4 + fsub;
            float4 w4 = W4[base4 + f * 2];                   // coalesced 8x128B per instr
            float x0 = xs[0][f], x1 = xs[1][f];              // LDS broadcast
            acc0.x = fmaf(x0, w4.x, acc0.x); acc0.y = fmaf(x0, w4.y, acc0.y);
            acc0.z = fmaf(x0, w4.z, acc0.z); acc0.w = fmaf(x0, w4.w, acc0.w);
            acc1.x = fmaf(x1, w4.x, acc1.x); acc1.y = fmaf(x1, w4.y, acc1.y);
            acc1.z = fmaf(x1, w4.z, acc1.z); acc1.w = fmaf(x1, w4.w, acc1.w);
        }
        #define RED4(A) \
            A.x += __shfl_xor(A.x, 16, 64); A.x += __shfl_xor(A.x, 32, 64); \
            A.y += __shfl_xor(A.y, 16, 64); A.y += __shfl_xor(A.y, 32, 64); \
            A.z += __shfl_xor(A.z, 16, 64); A.z += __shfl_xor(A.z, 32, 64); \
            A.w += __shfl_xor(A.w, 16, 64); A.w += __shfl_xor(A.w, 32, 64);
        RED4(acc0) RED4(acc1)
        #undef RED4
        if (fsub == 0) {
            int o = h * 8 + dq * 4;
            *(float4*)&part[wid][0][o] = acc0;
            *(float4*)&part[wid][1][o] = acc1;
        }
        __syncthreads();
        if (wid < 2) {                                       // wave wid finalizes row n0+wid
            int n = n0 + wid;
            float v = part[0][wid][lane] + part[1][wid][lane]
                    + part[2][wid][lane] + part[3][wid][lane];
            Wh[n * HD + lane] = v;
            float t1 = v * a1[lane];
            float t2 = v * a2[lane];
            for (int m = 1; m < 8; m <<= 1) {
                t1 += __shfl_xor(t1, m, 64);
                t2 += __shfl_xor(t2, m, 64);
            }
            if ((lane & 7) == 0) {
                int h2 = lane >> 3;
                s1t[n * 8 + h2] = t1;
                s2t[n * 8 + h2] = t2;
            }
        }
    }
}

// K2: attention + ELU + fused P/Q (R10 verbatim). 8 waves = 8 rows; W1 staged in LDS.
__global__ __launch_bounds__(512) void k_attn_pq(const float* __restrict__ Wh, const float* __restrict__ s1t,
                                                 const float* __restrict__ s2t, const int* __restrict__ nbr,
                                                 const int* __restrict__ cnt, const float* __restrict__ W1,
                                                 const float* __restrict__ b1, float* __restrict__ P,
                                                 float* __restrict__ Q) {
    __shared__ float W1s[2 * HD][HD];
    __shared__ int   jbuf[AROWS][CAP];
    __shared__ float ebuf[AROWS][8][CAPP];
    __shared__ float es[AROWS][HD];
    int tid = threadIdx.x;
    int wid = tid >> 6;
    int lane = tid & 63;
    int i = blockIdx.x * AROWS + wid;
    int h = lane >> 3, d = lane & 7;
    int ni = cnt[i];
    float s1i = s1t[i * 8 + h];
    for (int k = lane; k < CAP; k += 64)
        if (k < ni) jbuf[wid][k] = nbr[i * CAP + k];
    for (int idx = tid; idx < 2048; idx += 512)
        ((float4*)W1s)[idx] = ((const float4*)W1)[idx];
    __syncthreads();
    float mloc = -INFINITY;
    for (int k = d; k < ni; k += 8) {
        int j = jbuf[wid][k];
        float ev = s1i + s2t[j * 8 + h];
        ev = ev > 0.f ? ev : ALPHA * ev;
        ebuf[wid][h][k] = ev;
        mloc = fmaxf(mloc, ev);
    }
    mloc = fmaxf(mloc, __shfl_xor(mloc, 1, 8));
    mloc = fmaxf(mloc, __shfl_xor(mloc, 2, 8));
    mloc = fmaxf(mloc, __shfl_xor(mloc, 4, 8));
    __syncthreads();
    float denom = 0.f, acc = 0.f;
    for (int k = 0; k < ni; ++k) {
        float p = __expf(ebuf[wid][h][k] - mloc);
        denom += p;
        acc = fmaf(p, Wh[jbuf[wid][k] * HD + lane], acc);
    }
    float o = acc / denom;
    o = o > 0.f ? o : expm1f(o);
    es[wid][lane] = o;
    __syncthreads();
    float p = b1[lane], q = 0.f;
    #pragma unroll 8
    for (int k = 0; k < HD; ++k) {
        float e = es[wid][k];
        p = fmaf(e, W1s[k][lane], p);
        q = fmaf(e, W1s[HD + k][lane], q);
    }
    P[i * HD + lane] = p;
    Q[i * HD + lane] = q;
}

// K3: edge classifier; block sum atomically accumulated into out[0] (relaxed
// device-scope atomicAdd — cheap, unlike R5's release/acquire fences).
__global__ __launch_bounds__(256) void k_cls(const float* __restrict__ P, const float* __restrict__ Q,
                                             const int* __restrict__ L, const int* __restrict__ R,
                                             const int* __restrict__ label, const float* __restrict__ W2,
                                             const float* __restrict__ b2, float* __restrict__ out) {
    int tid = threadIdx.x;
    int sl = tid & 15;
    int g = (blockIdx.x * 256 + tid) >> 4;
    float2 wa = *(const float2*)&W2[(sl * 4 + 0) * 2];
    float2 wb = *(const float2*)&W2[(sl * 4 + 1) * 2];
    float2 wc = *(const float2*)&W2[(sl * 4 + 2) * 2];
    float2 wd = *(const float2*)&W2[(sl * 4 + 3) * 2];
    float b20 = b2[0], b21 = b2[1];

    int e0 = g, e1 = g + 32768, e2 = g + 65536;
    int ln0 = L[e0], rn0 = R[e0], lb0 = label[e0];
    int ln1 = L[e1], rn1 = R[e1], lb1 = label[e1];
    int ln2 = L[e2], rn2 = R[e2], lb2 = label[e2];
    float4 p0 = *(const float4*)&P[ln0 * HD + sl * 4];
    float4 q0 = *(const float4*)&Q[rn0 * HD + sl * 4];
    float4 p1 = *(const float4*)&P[ln1 * HD + sl * 4];
    float4 q1 = *(const float4*)&Q[rn1 * HD + sl * 4];
    float4 p2 = *(const float4*)&P[ln2 * HD + sl * 4];
    float4 q2 = *(const float4*)&Q[rn2 * HD + sl * 4];

    float v00 = fmaxf(p0.x + q0.x, 0.f), v01 = fmaxf(p0.y + q0.y, 0.f);
    float v02 = fmaxf(p0.z + q0.z, 0.f), v03 = fmaxf(p0.w + q0.w, 0.f);
    float v10 = fmaxf(p1.x + q1.x, 0.f), v11 = fmaxf(p1.y + q1.y, 0.f);
    float v12 = fmaxf(p1.z + q1.z, 0.f), v13 = fmaxf(p1.w + q1.w, 0.f);
    float v20 = fmaxf(p2.x + q2.x, 0.f), v21 = fmaxf(p2.y + q2.y, 0.f);
    float v22 = fmaxf(p2.z + q2.z, 0.f), v23 = fmaxf(p2.w + q2.w, 0.f);

    float t00 = v00 * wa.x + v01 * wb.x + v02 * wc.x + v03 * wd.x;
    float t01 = v00 * wa.y + v01 * wb.y + v02 * wc.y + v03 * wd.y;
    float t10 = v10 * wa.x + v11 * wb.x + v12 * wc.x + v13 * wd.x;
    float t11 = v10 * wa.y + v11 * wb.y + v12 * wc.y + v13 * wd.y;
    float t20 = v20 * wa.x + v21 * wb.x + v22 * wc.x + v23 * wd.x;
    float t21 = v20 * wa.y + v21 * wb.y + v22 * wc.y + v23 * wd.y;
    #pragma unroll
    for (int m = 1; m < 16; m <<= 1) {
        t00 += __shfl_xor(t00, m, 64);  t01 += __shfl_xor(t01, m, 64);
        t10 += __shfl_xor(t10, m, 64);  t11 += __shfl_xor(t11, m, 64);
        t20 += __shfl_xor(t20, m, 64);  t21 += __shfl_xor(t21, m, 64);
    }
    float sum;
    {
        float l0 = t00 + b20, l1 = t01 + b21;
        float mx = fmaxf(l0, l1);
        sum = mx + __logf(__expf(l0 - mx) + __expf(l1 - mx)) - (lb0 ? l1 : l0);
        l0 = t10 + b20; l1 = t11 + b21; mx = fmaxf(l0, l1);
        sum += mx + __logf(__expf(l0 - mx) + __expf(l1 - mx)) - (lb1 ? l1 : l0);
        l0 = t20 + b20; l1 = t21 + b21; mx = fmaxf(l0, l1);
        sum += mx + __logf(__expf(l0 - mx) + __expf(l1 - mx)) - (lb2 ? l1 : l0);
    }
    if (g + 98304 < NE) {                                    // tail; wave-uniform
        int e3 = g + 98304;
        int ln3 = L[e3], rn3 = R[e3], lb3 = label[e3];
        float4 p3 = *(const float4*)&P[ln3 * HD + sl * 4];
        float4 q3 = *(const float4*)&Q[rn3 * HD + sl * 4];
        float w0 = fmaxf(p3.x + q3.x, 0.f), w1 = fmaxf(p3.y + q3.y, 0.f);
        float w2 = fmaxf(p3.z + q3.z, 0.f), w3 = fmaxf(p3.w + q3.w, 0.f);
        float t30 = w0 * wa.x + w1 * wb.x + w2 * wc.x + w3 * wd.x;
        float t31 = w0 * wa.y + w1 * wb.y + w2 * wc.y + w3 * wd.y;
        #pragma unroll
        for (int m = 1; m < 16; m <<= 1) {
            t30 += __shfl_xor(t30, m, 64);  t31 += __shfl_xor(t31, m, 64);
        }
        float l0 = t30 + b20, l1 = t31 + b21;
        float mx = fmaxf(l0, l1);
        sum += mx + __logf(__expf(l0 - mx) + __expf(l1 - mx)) - (lb3 ? l1 : l0);
    }
    sum = (sl == 0) ? sum : 0.f;
    #pragma unroll
    for (int m = 1; m < 64; m <<= 1) sum += __shfl_xor(sum, m, 64);
    __shared__ float wsum[4];
    if ((tid & 63) == 0) wsum[tid >> 6] = sum;
    __syncthreads();
    if (tid == 0)
        atomicAdd(out, (wsum[0] + wsum[1] + wsum[2] + wsum[3]) * (1.f / (float)NE));
}

extern "C" void kernel_launch(void* const* d_in, const int* in_sizes, int n_in,
                              void* d_out, int out_size, void* d_ws, size_t ws_size,
                              hipStream_t stream) {
    const float* x     = (const float*)d_in[0];
    const float* adj   = (const float*)d_in[1];
    const int*   L     = (const int*)d_in[2];
    const int*   R     = (const int*)d_in[3];
    const int*   label = (const int*)d_in[4];
    const float* W     = (const float*)d_in[5];
    const float* a1    = (const float*)d_in[6];
    const float* a2    = (const float*)d_in[7];
    const float* W1    = (const float*)d_in[8];
    const float* b1    = (const float*)d_in[9];
    const float* W2    = (const float*)d_in[10];
    const float* b2    = (const float*)d_in[11];

    char* ws = (char*)d_ws;
    float* Wh       = (float*)(ws + 0);         //  786432 B
    float* s1t      = (float*)(ws + 786432);    //   98304 B   [N][8]
    float* s2t      = (float*)(ws + 884736);    //   98304 B   [N][8]
    int*   cnt      = (int*)  (ws + 983040);    //   12288 B
    int*   nbr      = (int*)  (ws + 995328);    // 1179648 B
    float* P        = (float*)(ws + 2174976);   //  786432 B
    float* Q        = (float*)(ws + 2961408);   //  786432 B
    float* outp     = (float*)d_out;

    k_stage1<<<WHB2 + NN, 256, 0, stream>>>(adj, x, W, a1, a2, nbr, cnt, Wh, s1t, s2t, outp);
    k_attn_pq<<<NN / AROWS, 512, 0, stream>>>(Wh, s1t, s2t, nbr, cnt, W1, b1, P, Q);
    k_cls<<<K5_BLOCKS, 256, 0, stream>>>(P, Q, L, R, label, W2, b2, outp);
}

// Round 18
// 34.387 us; speedup vs baseline: 10.3268x; 1.7593x over previous
//
#include <hip/hip_runtime.h>
#include <math.h>

#define NN 3072
#define FEAT 512
#define HD 64           // 8 heads x 8 dims
#define NE 100000
#define ALPHA 0.2f
#define CAP 96          // max neighbors per row (mean ~7)
#define CAPP 97         // padded for LDS bank spread
#define AROWS 8         // rows per attn block (8 waves)
#define WH_BLOCKS 768   // wh role: 4 rows per block
#define K5_BLOCKS 2048

// K1 (fused, 3840 blocks):
//   b < 768 : wh role — 4 rows, K split over 4 waves, coalesced float4-over-d W loads,
//             conflict-free xs[4][FEAT] staging + per-f LDS broadcast reads.
//   b >= 768: pre role — ONE adj row per block, 4 waves x 768 cols each.
__global__ __launch_bounds__(256) void k_stage1(const float* __restrict__ adj, const float* __restrict__ x,
                                                const float* __restrict__ W, const float* __restrict__ a1,
                                                const float* __restrict__ a2, int* __restrict__ nbr,
                                                int* __restrict__ cnt, float* __restrict__ Wh,
                                                float* __restrict__ s1t, float* __restrict__ s2t) {
    __shared__ float xs[4][FEAT];       // 8 KB (wh role)
    __shared__ float part[4][4][HD];    // 4 KB (wh role)
    __shared__ int   wcnt[4];           // pre role
    int b = blockIdx.x;
    int tid = threadIdx.x;
    int wid = tid >> 6, lane = tid & 63;

    if (b >= WH_BLOCKS) {
        // ---- pre role: row i, wave wid scans cols [wid*768, wid*768+768) ----
        int i = b - WH_BLOCKS;
        const float4* row4 = (const float4*)&adj[(size_t)i * NN];
        float4 v[3];
        #pragma unroll
        for (int c = 0; c < 3; ++c) v[c] = row4[wid * 192 + c * 64 + lane];  // independent
        unsigned long long lmask = (1ull << lane) - 1ull;
        int wc = 0;
        unsigned long long masks[12];
        #pragma unroll
        for (int c = 0; c < 3; ++c) {
            #pragma unroll
            for (int k = 0; k < 4; ++k) {
                float vk = k == 0 ? v[c].x : k == 1 ? v[c].y : k == 2 ? v[c].z : v[c].w;
                unsigned long long m = __ballot(vk > 0.f);
                masks[c * 4 + k] = m;
                wc += __popcll(m);
            }
        }
        if (lane == 0) wcnt[wid] = wc;
        __syncthreads();
        int base = 0;
        #pragma unroll
        for (int w2 = 0; w2 < 4; ++w2) if (w2 < wid) base += wcnt[w2];
        #pragma unroll
        for (int c = 0; c < 3; ++c) {
            #pragma unroll
            for (int k = 0; k < 4; ++k) {
                unsigned long long m = masks[c * 4 + k];
                if ((m >> lane) & 1ull) {
                    int pos = base + __popcll(m & lmask);
                    if (pos < CAP) nbr[i * CAP + pos] = wid * 768 + c * 256 + lane * 4 + k;
                }
                base += __popcll(m);
            }
        }
        if (tid == 0) {
            int tot = wcnt[0] + wcnt[1] + wcnt[2] + wcnt[3];
            cnt[i] = tot < CAP ? tot : CAP;
        }
    } else {
        // ---- wh role: rows n0..n0+3, K split over 4 waves, float4-over-d W loads ----
        int n0 = b * 4;
        for (int idx = tid; idx < 512; idx += 256) {          // stage x (conflict-free)
            int r = idx >> 7, fq = idx & 127;
            *(float4*)&xs[r][fq * 4] = ((const float4*)x)[(size_t)(n0 + r) * (FEAT / 4) + fq];
        }
        __syncthreads();
        // lane decomposition: fsub = f-interleave, (h,dq) = output quad
        int fsub = lane >> 4, h = (lane >> 1) & 7, dq = lane & 1;
        const float4* W4 = (const float4*)W;                  // W[h][f][d] as float4 over d
        int base4 = h * 1024 + dq;                            // + f*2 indexes W[h][f][dq*4..+3]
        int f0 = wid * (FEAT / 4);
        float4 acc0 = {0.f,0.f,0.f,0.f}, acc1 = acc0, acc2 = acc0, acc3 = acc0;
        #pragma unroll 4
        for (int f4 = 0; f4 < 32; ++f4) {
            int f = f0 + f4 * 4 + fsub;
            float4 w4 = W4[base4 + f * 2];                    // coalesced: 8x128B per instr
            float x0 = xs[0][f], x1 = xs[1][f], x2 = xs[2][f], x3 = xs[3][f];  // LDS broadcast
            acc0.x = fmaf(x0, w4.x, acc0.x); acc0.y = fmaf(x0, w4.y, acc0.y);
            acc0.z = fmaf(x0, w4.z, acc0.z); acc0.w = fmaf(x0, w4.w, acc0.w);
            acc1.x = fmaf(x1, w4.x, acc1.x); acc1.y = fmaf(x1, w4.y, acc1.y);
            acc1.z = fmaf(x1, w4.z, acc1.z); acc1.w = fmaf(x1, w4.w, acc1.w);
            acc2.x = fmaf(x2, w4.x, acc2.x); acc2.y = fmaf(x2, w4.y, acc2.y);
            acc2.z = fmaf(x2, w4.z, acc2.z); acc2.w = fmaf(x2, w4.w, acc2.w);
            acc3.x = fmaf(x3, w4.x, acc3.x); acc3.y = fmaf(x3, w4.y, acc3.y);
            acc3.z = fmaf(x3, w4.z, acc3.z); acc3.w = fmaf(x3, w4.w, acc3.w);
        }
        // butterfly-reduce over the 4 fsub groups (fixed order -> deterministic)
        #define RED4(A) \
            A.x += __shfl_xor(A.x, 16, 64); A.x += __shfl_xor(A.x, 32, 64); \
            A.y += __shfl_xor(A.y, 16, 64); A.y += __shfl_xor(A.y, 32, 64); \
            A.z += __shfl_xor(A.z, 16, 64); A.z += __shfl_xor(A.z, 32, 64); \
            A.w += __shfl_xor(A.w, 16, 64); A.w += __shfl_xor(A.w, 32, 64);
        RED4(acc0) RED4(acc1) RED4(acc2) RED4(acc3)
        #undef RED4
        if (fsub == 0) {                                      // 16 lanes hold the wave's result
            int o = h * 8 + dq * 4;
            *(float4*)&part[wid][0][o] = acc0;
            *(float4*)&part[wid][1][o] = acc1;
            *(float4*)&part[wid][2][o] = acc2;
            *(float4*)&part[wid][3][o] = acc3;
        }
        __syncthreads();
        int n = n0 + wid;                                     // wave wid finalizes row n0+wid
        float v = part[0][wid][lane] + part[1][wid][lane] + part[2][wid][lane] + part[3][wid][lane];
        Wh[n * HD + lane] = v;
        float t1 = v * a1[lane];
        float t2 = v * a2[lane];
        for (int m = 1; m < 8; m <<= 1) {
            t1 += __shfl_xor(t1, m, 64);
            t2 += __shfl_xor(t2, m, 64);
        }
        if ((lane & 7) == 0) {
            int h2 = lane >> 3;
            s1t[n * 8 + h2] = t1;
            s2t[n * 8 + h2] = t2;
        }
    }
}

// K2: attention + ELU + fused P/Q. 8 waves = 8 rows per block; W1 staged in LDS.
__global__ __launch_bounds__(512) void k_attn_pq(const float* __restrict__ Wh, const float* __restrict__ s1t,
                                                 const float* __restrict__ s2t, const int* __restrict__ nbr,
                                                 const int* __restrict__ cnt, const float* __restrict__ W1,
                                                 const float* __restrict__ b1, float* __restrict__ P,
                                                 float* __restrict__ Q) {
    __shared__ float W1s[2 * HD][HD];
    __shared__ int   jbuf[AROWS][CAP];
    __shared__ float ebuf[AROWS][8][CAPP];
    __shared__ float es[AROWS][HD];
    int tid = threadIdx.x;
    int wid = tid >> 6;
    int lane = tid & 63;
    int i = blockIdx.x * AROWS + wid;
    int h = lane >> 3, d = lane & 7;
    int ni = cnt[i];
    float s1i = s1t[i * 8 + h];
    for (int k = lane; k < CAP; k += 64)
        if (k < ni) jbuf[wid][k] = nbr[i * CAP + k];
    for (int idx = tid; idx < 2048; idx += 512)
        ((float4*)W1s)[idx] = ((const float4*)W1)[idx];
    __syncthreads();
    float mloc = -INFINITY;
    for (int k = d; k < ni; k += 8) {
        int j = jbuf[wid][k];
        float ev = s1i + s2t[j * 8 + h];
        ev = ev > 0.f ? ev : ALPHA * ev;
        ebuf[wid][h][k] = ev;
        mloc = fmaxf(mloc, ev);
    }
    mloc = fmaxf(mloc, __shfl_xor(mloc, 1, 8));
    mloc = fmaxf(mloc, __shfl_xor(mloc, 2, 8));
    mloc = fmaxf(mloc, __shfl_xor(mloc, 4, 8));
    __syncthreads();
    float denom = 0.f, acc = 0.f;
    for (int k = 0; k < ni; ++k) {
        float p = __expf(ebuf[wid][h][k] - mloc);
        denom += p;
        acc = fmaf(p, Wh[jbuf[wid][k] * HD + lane], acc);
    }
    float o = acc / denom;
    o = o > 0.f ? o : expm1f(o);
    es[wid][lane] = o;
    __syncthreads();
    float p = b1[lane], q = 0.f;
    #pragma unroll 8
    for (int k = 0; k < HD; ++k) {
        float e = es[wid][k];
        p = fmaf(e, W1s[k][lane], p);
        q = fmaf(e, W1s[HD + k][lane], q);
    }
    P[i * HD + lane] = p;
    Q[i * HD + lane] = q;
}

// K3: 16 lanes per edge; 3 edges + tail processed concurrently; branchless lse.
__global__ __launch_bounds__(256) void k_cls(const float* __restrict__ P, const float* __restrict__ Q,
                                             const int* __restrict__ L, const int* __restrict__ R,
                                             const int* __restrict__ label, const float* __restrict__ W2,
                                             const float* __restrict__ b2, float* __restrict__ partials) {
    int tid = threadIdx.x;
    int sl = tid & 15;
    int g = (blockIdx.x * 256 + tid) >> 4;
    float2 wa = *(const float2*)&W2[(sl * 4 + 0) * 2];
    float2 wb = *(const float2*)&W2[(sl * 4 + 1) * 2];
    float2 wc = *(const float2*)&W2[(sl * 4 + 2) * 2];
    float2 wd = *(const float2*)&W2[(sl * 4 + 3) * 2];
    float b20 = b2[0], b21 = b2[1];

    int e0 = g, e1 = g + 32768, e2 = g + 65536;
    int ln0 = L[e0], rn0 = R[e0], lb0 = label[e0];
    int ln1 = L[e1], rn1 = R[e1], lb1 = label[e1];
    int ln2 = L[e2], rn2 = R[e2], lb2 = label[e2];
    float4 p0 = *(const float4*)&P[ln0 * HD + sl * 4];
    float4 q0 = *(const float4*)&Q[rn0 * HD + sl * 4];
    float4 p1 = *(const float4*)&P[ln1 * HD + sl * 4];
    float4 q1 = *(const float4*)&Q[rn1 * HD + sl * 4];
    float4 p2 = *(const float4*)&P[ln2 * HD + sl * 4];
    float4 q2 = *(const float4*)&Q[rn2 * HD + sl * 4];

    float v00 = fmaxf(p0.x + q0.x, 0.f), v01 = fmaxf(p0.y + q0.y, 0.f);
    float v02 = fmaxf(p0.z + q0.z, 0.f), v03 = fmaxf(p0.w + q0.w, 0.f);
    float v10 = fmaxf(p1.x + q1.x, 0.f), v11 = fmaxf(p1.y + q1.y, 0.f);
    float v12 = fmaxf(p1.z + q1.z, 0.f), v13 = fmaxf(p1.w + q1.w, 0.f);
    float v20 = fmaxf(p2.x + q2.x, 0.f), v21 = fmaxf(p2.y + q2.y, 0.f);
    float v22 = fmaxf(p2.z + q2.z, 0.f), v23 = fmaxf(p2.w + q2.w, 0.f);

    float t00 = v00 * wa.x + v01 * wb.x + v02 * wc.x + v03 * wd.x;
    float t01 = v00 * wa.y + v01 * wb.y + v02 * wc.y + v03 * wd.y;
    float t10 = v10 * wa.x + v11 * wb.x + v12 * wc.x + v13 * wd.x;
    float t11 = v10 * wa.y + v11 * wb.y + v12 * wc.y + v13 * wd.y;
    float t20 = v20 * wa.x + v21 * wb.x + v22 * wc.x + v23 * wd.x;
    float t21 = v20 * wa.y + v21 * wb.y + v22 * wc.y + v23 * wd.y;
    #pragma unroll
    for (int m = 1; m < 16; m <<= 1) {
        t00 += __shfl_xor(t00, m, 64);  t01 += __shfl_xor(t01, m, 64);
        t10 += __shfl_xor(t10, m, 64);  t11 += __shfl_xor(t11, m, 64);
        t20 += __shfl_xor(t20, m, 64);  t21 += __shfl_xor(t21, m, 64);
    }
    float sum;
    {
        float l0 = t00 + b20, l1 = t01 + b21;
        float mx = fmaxf(l0, l1);
        sum = mx + __logf(__expf(l0 - mx) + __expf(l1 - mx)) - (lb0 ? l1 : l0);
        l0 = t10 + b20; l1 = t11 + b21; mx = fmaxf(l0, l1);
        sum += mx + __logf(__expf(l0 - mx) + __expf(l1 - mx)) - (lb1 ? l1 : l0);
        l0 = t20 + b20; l1 = t21 + b21; mx = fmaxf(l0, l1);
        sum += mx + __logf(__expf(l0 - mx) + __expf(l1 - mx)) - (lb2 ? l1 : l0);
    }
    if (g + 98304 < NE) {                                // tail edge; wave-uniform (1696%4==0)
        int e3 = g + 98304;
        int ln3 = L[e3], rn3 = R[e3], lb3 = label[e3];
        float4 p3 = *(const float4*)&P[ln3 * HD + sl * 4];
        float4 q3 = *(const float4*)&Q[rn3 * HD + sl * 4];
        float w0 = fmaxf(p3.x + q3.x, 0.f), w1 = fmaxf(p3.y + q3.y, 0.f);
        float w2 = fmaxf(p3.z + q3.z, 0.f), w3 = fmaxf(p3.w + q3.w, 0.f);
        float t30 = w0 * wa.x + w1 * wb.x + w2 * wc.x + w3 * wd.x;
        float t31 = w0 * wa.y + w1 * wb.y + w2 * wc.y + w3 * wd.y;
        #pragma unroll
        for (int m = 1; m < 16; m <<= 1) {
            t30 += __shfl_xor(t30, m, 64);  t31 += __shfl_xor(t31, m, 64);
        }
        float l0 = t30 + b20, l1 = t31 + b21;
        float mx = fmaxf(l0, l1);
        sum += mx + __logf(__expf(l0 - mx) + __expf(l1 - mx)) - (lb3 ? l1 : l0);
    }
    sum = (sl == 0) ? sum : 0.f;
    #pragma unroll
    for (int m = 1; m < 64; m <<= 1) sum += __shfl_xor(sum, m, 64);
    __shared__ float wsum[4];
    if ((tid & 63) == 0) wsum[tid >> 6] = sum;
    __syncthreads();
    if (tid == 0) partials[blockIdx.x] = wsum[0] + wsum[1] + wsum[2] + wsum[3];
}

// K4: reduce 2048 partials -> mean
__global__ __launch_bounds__(1024) void k_reduce(const float* __restrict__ partials, float* __restrict__ out) {
    __shared__ float sh[1024];
    int t = threadIdx.x;
    sh[t] = partials[t] + partials[t + 1024];
    __syncthreads();
    for (int s = 512; s > 0; s >>= 1) {
        if (t < s) sh[t] += sh[t + s];
        __syncthreads();
    }
    if (t == 0) out[0] = sh[0] / (float)NE;
}

extern "C" void kernel_launch(void* const* d_in, const int* in_sizes, int n_in,
                              void* d_out, int out_size, void* d_ws, size_t ws_size,
                              hipStream_t stream) {
    const float* x     = (const float*)d_in[0];
    const float* adj   = (const float*)d_in[1];
    const int*   L     = (const int*)d_in[2];
    const int*   R     = (const int*)d_in[3];
    const int*   label = (const int*)d_in[4];
    const float* W     = (const float*)d_in[5];
    const float* a1    = (const float*)d_in[6];
    const float* a2    = (const float*)d_in[7];
    const float* W1    = (const float*)d_in[8];
    const float* b1    = (const float*)d_in[9];
    const float* W2    = (const float*)d_in[10];
    const float* b2    = (const float*)d_in[11];

    char* ws = (char*)d_ws;
    float* Wh       = (float*)(ws + 0);         //  786432 B
    float* s1t      = (float*)(ws + 786432);    //   98304 B   [N][8]
    float* s2t      = (float*)(ws + 884736);    //   98304 B   [N][8]
    int*   cnt      = (int*)  (ws + 983040);    //   12288 B
    int*   nbr      = (int*)  (ws + 995328);    // 1179648 B
    float* P        = (float*)(ws + 2174976);   //  786432 B
    float* Q        = (float*)(ws + 2961408);   //  786432 B
    float* partials = (float*)(ws + 3747840);   //    8192 B

    k_stage1<<<WH_BLOCKS + NN, 256, 0, stream>>>(adj, x, W, a1, a2, nbr, cnt, Wh, s1t, s2t);
    k_attn_pq<<<NN / AROWS, 512, 0, stream>>>(Wh, s1t, s2t, nbr, cnt, W1, b1, P, Q);
    k_cls<<<K5_BLOCKS, 256, 0, stream>>>(P, Q, L, R, label, W2, b2, partials);
    k_reduce<<<1, 1024, 0, stream>>>(partials, (float*)d_out);
}